// Round 5
// baseline (5702.634 us; speedup 1.0000x reference)
//
#include <hip/hip_runtime.h>

typedef float f32x4  __attribute__((ext_vector_type(4)));
typedef float f32x16 __attribute__((ext_vector_type(16)));
typedef short short8 __attribute__((ext_vector_type(8)));
typedef int   intx4  __attribute__((ext_vector_type(4)));

#define TT 1024
#define DD 512
#define BTD (32u*1024u*512u)
#define NS 8               // dcomm ring slots
#define SLOT_SH 16384      // shorts per slot (32KB)

__device__ __forceinline__ unsigned short f2bf(float f){
  unsigned int u = __float_as_uint(f);
  u += 0x7FFFu + ((u >> 16) & 1u);          // round-to-nearest-even
  return (unsigned short)(u >> 16);
}
__device__ __forceinline__ float bf2f(unsigned short s){
  return __uint_as_float(((unsigned)s) << 16);
}
__device__ __forceinline__ float fast_tanh(float x){
  float ax = fabsf(x);
  float e  = __expf(2.0f*ax);
  float r  = 1.0f - 2.0f/(e + 1.0f);
  return x < 0.f ? -r : r;
}

// ---------------- prep: z, packed weights, d_init (fragment layout), flags ----------------
__global__ void prep_misc_k(const float* __restrict__ A, const float* __restrict__ noise,
                            const float* __restrict__ Wd, const float* __restrict__ Wz,
                            const float* __restrict__ Wdz, const float* __restrict__ Whd,
                            const float* __restrict__ init_h,
                            unsigned short* __restrict__ zbf, unsigned short* __restrict__ Wu,
                            unsigned short* __restrict__ Wp, unsigned short* __restrict__ dcomm,
                            int* __restrict__ flags){
  const unsigned NZ = 2097152u, NWU = 294912u, NWP = 327680u, ND = 16384u;
  const unsigned NT = NZ + NWU + NWP + ND + 32u;
  for (unsigned i = blockIdx.x*blockDim.x + threadIdx.x; i < NT; i += gridDim.x*blockDim.x){
    if (i < NZ){                                   // z = tanh(mu_in_q) + noise*exp(ln_q)
      unsigned m = i >> 6, zi = i & 63u;
      float muin = A[(size_t)m*128u + zi];
      float ln   = A[(size_t)m*128u + 64u + zi];
      zbf[i] = f2bf(fast_tanh(muin) + noise[i]*__expf(ln));
    } else if (i < NZ+NWU){                        // Wu[c][kk]: [Whd | Wz], [512][576]
      unsigned j = i - NZ;
      unsigned c = j / 576u, kk = j - c*576u;
      float v = (kk < 512u) ? Whd[(size_t)c*512u + kk] : Wz[(size_t)c*64u + (kk-512u)];
      Wu[j] = f2bf(v);
    } else if (i < NZ+NWU+NWP){                    // Wp[c][k]: [Wd | Wdz interleaved], [640][512]
      unsigned j = i - (NZ+NWU);
      unsigned c = j >> 9, k = j & 511u;
      float v;
      if (c < 512u) v = Wd[(size_t)c*512u + k];
      else {
        unsigned jj = c - 512u, g = jj >> 5, w = jj & 31u;
        unsigned z = g*16u + (w & 15u), half = w >> 4;
        v = Wdz[(size_t)(half*64u + z)*512u + k];
      }
      Wp[j] = f2bf(v);
    } else if (i < NZ+NWU+NWP+ND){                 // d_{-1} = tanh(init_h) -> ring slot 7, fragment layout
      unsigned j = i - (NZ+NWU+NWP);
      unsigned b = j >> 9, c = j & 511u;
      unsigned idx = ((c>>4)<<9) + (((c>>3)&1u)<<8) + (b<<3) + (c&7u);
      dcomm[(NS-1u)*SLOT_SH + idx] = f2bf(fast_tanh(init_h[j]));
    } else {
      unsigned j = i - (NZ+NWU+NWP+ND);
      if (j < 32u) flags[j] = 0;
    }
  }
}

// ---------------- wnll_init_h -> d_out[BTD] ----------------
__global__ void wnll_k(const float* __restrict__ init_h, const float* __restrict__ mu,
                       float* __restrict__ dout){
  __shared__ float red[256];
  float s = 0.f;
  for (unsigned i = threadIdx.x; i < 16384u; i += 256u){
    float x = init_h[i] - mu[i & 511u];
    s += 0.5f*x*x;
  }
  red[threadIdx.x] = s; __syncthreads();
  for (int st = 128; st > 0; st >>= 1){
    if ((int)threadIdx.x < st) red[threadIdx.x] += red[threadIdx.x + st];
    __syncthreads();
  }
  if (threadIdx.x == 0){
    float nll = (red[0] + 16384.0f*0.91893853320467274f) / 512.0f;
    dout[(size_t)BTD] = 1e-3f * nll;
  }
}

// ---------------- U = (X @ Wu^T + bias)/tau  -> bf16 fragment-layout Ufrag ----------------
// Ufrag element (t, w=pc>>5, l=hi*32+(pc&31), r) at ((t*16+w)*64+l)*16 + r,
// where b = (r&3) + 8*(r>>2) + 4*hi.
__global__ __launch_bounds__(256) void gemm_u_k(
    const float* __restrict__ hd,             // [32768][512] f32
    const unsigned short* __restrict__ Xz,    // [32768][64]  bf16
    const unsigned short* __restrict__ Wu,    // [512][576]   bf16
    const float* __restrict__ bias,
    unsigned short* __restrict__ Ufrag)       // bf16 frag layout
{
  __shared__ __align__(16) unsigned short Xs[128][40];
  __shared__ __align__(16) unsigned short Ws[128][40];
  const int bm = blockIdx.x >> 2;
  const int bn = blockIdx.x & 3;
  const int tid = threadIdx.x;
  const int lane = tid & 63;
  const int wv = tid >> 6;
  const int m0 = (wv >> 1) * 64, c0 = (wv & 1) * 64;
  f32x4 acc[4][4];
  #pragma unroll
  for (int i=0;i<4;++i)
    #pragma unroll
    for (int j=0;j<4;++j)
      #pragma unroll
      for (int r=0;r<4;++r) acc[i][j][r] = 0.f;

  const int sm = tid >> 1;
  const int sk = (tid & 1) * 16;
  for (int kt = 0; kt < 18; ++kt){
    __syncthreads();
    {
      int mg = bm*128 + sm;
      if (kt < 16){
        const float* src = hd + (size_t)mg*512u + (unsigned)(kt*32 + sk);
        uint2 o[4];
        #pragma unroll
        for (int q=0;q<4;++q){
          f32x4 v = *reinterpret_cast<const f32x4*>(src + 4*q);
          o[q].x = (unsigned)f2bf(v[0]) | ((unsigned)f2bf(v[1])<<16);
          o[q].y = (unsigned)f2bf(v[2]) | ((unsigned)f2bf(v[3])<<16);
        }
        *reinterpret_cast<uint4*>(&Xs[sm][sk])   = make_uint4(o[0].x,o[0].y,o[1].x,o[1].y);
        *reinterpret_cast<uint4*>(&Xs[sm][sk+8]) = make_uint4(o[2].x,o[2].y,o[3].x,o[3].y);
      } else {
        const unsigned short* src = Xz + (size_t)mg*64u + (unsigned)((kt-16)*32 + sk);
        uint4 v0 = *reinterpret_cast<const uint4*>(src);
        uint4 v1 = *reinterpret_cast<const uint4*>(src + 8);
        *reinterpret_cast<uint4*>(&Xs[sm][sk])   = v0;
        *reinterpret_cast<uint4*>(&Xs[sm][sk+8]) = v1;
      }
      int cg = bn*128 + sm;
      const unsigned short* wsrc = Wu + (size_t)cg*576u + (unsigned)(kt*32 + sk);
      uint4 w0 = *reinterpret_cast<const uint4*>(wsrc);
      uint4 w1 = *reinterpret_cast<const uint4*>(wsrc + 8);
      *reinterpret_cast<uint4*>(&Ws[sm][sk])   = w0;
      *reinterpret_cast<uint4*>(&Ws[sm][sk+8]) = w1;
    }
    __syncthreads();
    short8 af[4], bf[4];
    #pragma unroll
    for (int i=0;i<4;++i)
      af[i] = *reinterpret_cast<const short8*>(&Xs[m0 + i*16 + (lane&15)][(lane>>4)*8]);
    #pragma unroll
    for (int j=0;j<4;++j)
      bf[j] = *reinterpret_cast<const short8*>(&Ws[c0 + j*16 + (lane&15)][(lane>>4)*8]);
    #pragma unroll
    for (int i=0;i<4;++i)
      #pragma unroll
      for (int j=0;j<4;++j)
        acc[i][j] = __builtin_amdgcn_mfma_f32_16x16x32_bf16(af[i], bf[j], acc[i][j], 0, 0, 0);
  }
  #pragma unroll
  for (int j=0;j<4;++j){
    int cg = bn*128 + c0 + j*16 + (lane&15);
    float bia  = bias[cg];
    float itau = (cg < 256) ? 0.25f : 0.5f;
    int w = cg >> 5, c = cg & 31;
    #pragma unroll
    for (int i=0;i<4;++i){
      int mbase = bm*128 + m0 + i*16 + (lane>>4)*4;
      int b  = mbase >> 10;
      int t0 = mbase & 1023;
      int hi = (b>>2) & 1;
      int ridx = (b&3) + 4*(b>>3);
      #pragma unroll
      for (int r=0;r<4;++r){
        size_t idx = (((size_t)(t0+r)*16 + w)*64 + (hi*32 + c))*16 + ridx;
        Ufrag[idx] = f2bf((acc[i][j][r] + bia) * itau);
      }
    }
  }
}

// ---------------- persistent serial recurrence ----------------
// grid = 22 WGs x 256 threads.
//   WG 0..15 (wave 0 only): D-column workers, 32 cols each.
//   WG 16..19 (wave 0 only): prior columns + KL.
//   WG 20..21 (4 waves): d_seq writers consuming the dcomm ring (7-step slack).
// Fabric: system-scope (sc0 sc1) uncached b128 traffic + vmcnt(0) release.
// Workers touch ONLY dcomm/flags/Ufrag: poll-vmcnt drains exactly 1 load.
__global__ __launch_bounds__(256,1) void recur_k(
    float* __restrict__ dout, const float* __restrict__ A, const float* __restrict__ init_h,
    const unsigned short* __restrict__ Wp, const unsigned short* __restrict__ Ufrag,
    unsigned short* __restrict__ dcomm, int* __restrict__ flags)
{
  __shared__ __align__(16) unsigned short tl[32][40];
  const int wg = blockIdx.x;

  // ================= writer WGs =================
  if (wg >= 20){
    const int tid  = threadIdx.x;
    const int lane = tid & 63;
    const int wid  = (wg - 20)*4 + (tid >> 6);   // 0..7
    int* const myflag = &flags[20 + (wg - 20)];
    const int b = lane & 31;
    const int pcq0 = (wid*4)*16 + (lane>>5)*8;
    for (int t = 0; t < TT; ++t){
      // wait for all worker flags >= t+1 (slot t%NS fully written)
      const int* fp = flags + ((lane < 16) ? lane : 0);
      for (;;){
        int f;
        asm volatile("global_load_dword %0, %1, off sc0 sc1\n\t"
                     "s_waitcnt vmcnt(0)"
                     : "=&v"(f) : "v"(fp) : "memory");
        if (__all(f >= t+1)) break;
      }
      // uncached gather of this wave's 4KB of the slot
      const char* base = (const char*)(dcomm + (t & (NS-1))*SLOT_SH) + wid*4096 + lane*16;
      intx4 dqi[4];
      asm volatile(
        "global_load_dwordx4 %0, %4, off sc0 sc1\n\t"
        "global_load_dwordx4 %1, %4, off offset:1024 sc0 sc1\n\t"
        "global_load_dwordx4 %2, %4, off offset:2048 sc0 sc1\n\t"
        "global_load_dwordx4 %3, %4, off offset:3072 sc0 sc1"
        : "=&v"(dqi[0]), "=&v"(dqi[1]), "=&v"(dqi[2]), "=&v"(dqi[3])
        : "v"(base) : "memory");
      asm volatile("s_waitcnt vmcnt(0)" ::: "memory");
      __builtin_amdgcn_sched_barrier(0);
      __syncthreads();
      if (tid == 0){
        int val = t + 1;
        asm volatile("global_store_dword %0, %1, off sc0 sc1"
                     :: "v"(myflag), "v"(val) : "memory");
      }
      // expand bf16 -> f32 d_seq (plain cached stores, drain lazily)
      float* drow = dout + ((size_t)b*TT + t)*DD + pcq0;
      #pragma unroll
      for (int q=0;q<4;++q){
        union { intx4 i; short8 s; } cv; cv.i = dqi[q];
        f32x4 o0, o1;
        #pragma unroll
        for (int e=0;e<4;++e){
          o0[e] = bf2f((unsigned short)cv.s[e]);
          o1[e] = bf2f((unsigned short)cv.s[4+e]);
        }
        *reinterpret_cast<f32x4*>(drow + q*16)     = o0;
        *reinterpret_cast<f32x4*>(drow + q*16 + 4) = o1;
      }
    }
    return;
  }

  // ================= worker / KL WGs (wave 0 only) =================
  if (threadIdx.x >= 64) return;
  const int lane = threadIdx.x;
  const bool isKL = (wg >= 16);
  const int pc    = wg*32 + (lane & 31);      // packed column 0..639
  const int khalf = (lane >> 5) * 8;
  const int bof   = (lane >> 5) * 4;

  // weights resident in VGPRs: 32 B-fragments of 8 bf16 (pinned: no remat)
  short8 wfrag[32];
  #pragma unroll
  for (int kc = 0; kc < 32; ++kc)
    wfrag[kc] = *reinterpret_cast<const short8*>(Wp + (size_t)pc*512u + (unsigned)(kc*16 + khalf));
  #pragma unroll
  for (int kc = 0; kc < 32; ++kc)
    asm volatile("" : "+v"(wfrag[kc]));

  const float dec  = (pc < 256) ? 0.75f : 0.5f;
  const float itau = (pc < 256) ? 0.25f : 0.5f;

  float h[16];
  if (!isKL){
    #pragma unroll
    for (int r=0;r<16;++r){
      int b = (r&3) + 8*(r>>2) + bof;
      h[r] = init_h[b*512 + pc];
    }
  }
  const int  zidx   = (wg - 16)*16 + (lane & 15);
  const bool muLane = ((lane & 16) == 0);
  float kacc = 0.f;

  // KL step-0 posterior prefetch
  float aqm[16], aql[16];
  if (isKL){
    #pragma unroll
    for (int r=0;r<16;++r){
      int b = (r&3) + 8*(r>>2) + bof;
      const float* ap = A + ((size_t)b*TT + 0)*128u;
      aqm[r] = ap[zidx]; aql[r] = ap[64 + zidx];
    }
  }

  // poll mapping: lanes 0..15 worker flags (thr t), 16..19 KL (t-1), 20..21 writers (t-7)
  int fidx, thro;
  if (lane < 16)      { fidx = lane; thro = 0; }
  else if (lane < 20) { fidx = lane; thro = -1; }
  else if (lane < 22) { fidx = lane; thro = -7; }
  else                { fidx = 0;    thro = 0; }
  const int* fp = flags + fidx;
  int* const myflag = &flags[wg];

  union CV { intx4 i; short8 s; };

  for (int t = 0; t < TT; ++t){
    if (t > 0){
      const int thr = t + thro;
      for (;;){
        int f;
        asm volatile("global_load_dword %0, %1, off sc0 sc1\n\t"
                     "s_waitcnt vmcnt(0)"
                     : "=&v"(f) : "v"(fp) : "memory");
        if (__all(f >= thr)) break;
      }
    }

    // uncached coalesced gather of d_{t-1} fragments
    const char* base = (const char*)dcomm + ((t-1) & (NS-1))*32768 + lane*16;
    intx4 fi[32];
    #pragma unroll
    for (int g = 0; g < 8; ++g){
      const char* bp = base + g*4096;
      asm volatile(
        "global_load_dwordx4 %0, %4, off sc0 sc1\n\t"
        "global_load_dwordx4 %1, %4, off offset:1024 sc0 sc1\n\t"
        "global_load_dwordx4 %2, %4, off offset:2048 sc0 sc1\n\t"
        "global_load_dwordx4 %3, %4, off offset:3072 sc0 sc1"
        : "=&v"(fi[4*g]), "=&v"(fi[4*g+1]), "=&v"(fi[4*g+2]), "=&v"(fi[4*g+3])
        : "v"(bp) : "memory");
    }
    // U slice for this step (cached, contiguous, compiler-managed wait)
    short8 us0, us1;
    if (!isKL){
      const unsigned short* up = Ufrag + (((size_t)t*16 + wg)*64 + lane)*16u;
      us0 = *reinterpret_cast<const short8*>(up);
      us1 = *reinterpret_cast<const short8*>(up + 8);
    }
    asm volatile("s_waitcnt vmcnt(0)" ::: "memory");
    __builtin_amdgcn_sched_barrier(0);

    if (isKL){
      // publish "reads done" early: KL drops off the critical path
      if (lane == 0){
        int val = t + 1;
        asm volatile("global_store_dword %0, %1, off sc0 sc1"
                     :: "v"(myflag), "v"(val) : "memory");
      }
    }

    // P = d_{t-1} @ W_slice  (two interleaved MFMA chains)
    f32x16 acc0, acc1;
    #pragma unroll
    for (int q=0;q<16;++q){ acc0[q]=0.f; acc1[q]=0.f; }
    #pragma unroll
    for (int kc=0;kc<16;++kc){
      CV c0, c1; c0.i = fi[2*kc]; c1.i = fi[2*kc+1];
      acc0 = __builtin_amdgcn_mfma_f32_32x32x16_bf16(c0.s, wfrag[2*kc  ], acc0, 0, 0, 0);
      acc1 = __builtin_amdgcn_mfma_f32_32x32x16_bf16(c1.s, wfrag[2*kc+1], acc1, 0, 0, 0);
    }

    if (!isKL){
      float dv[16];
      #pragma unroll
      for (int r=0;r<16;++r){
        float P = acc0[r] + acc1[r];
        float uu = bf2f((unsigned short)((r < 8) ? us0[r] : us1[r-8]));
        h[r]  = dec*h[r] + P*itau + uu;
        dv[r] = fast_tanh(h[r]);
      }
      // in-wave transpose via LDS: tl[batch][local col]
      #pragma unroll
      for (int r=0;r<16;++r){
        int b = (r&3) + 8*(r>>2) + bof;
        tl[b][lane & 31] = f2bf(dv[r]);
      }
      // two coalesced b128 system-scope stores into fragment-layout dcomm
      {
        unsigned short* ds = dcomm + (t & (NS-1))*SLOT_SH + (2*wg)*512 + lane*8;
        short8 s0 = *reinterpret_cast<const short8*>(&tl[lane & 31][khalf]);
        short8 s1 = *reinterpret_cast<const short8*>(&tl[lane & 31][16 + khalf]);
        asm volatile("global_store_dwordx4 %0, %2, off sc0 sc1\n\t"
                     "global_store_dwordx4 %1, %3, off sc0 sc1"
                     :: "v"(ds), "v"(ds + 512), "v"(s0), "v"(s1) : "memory");
      }
      // release: drain exactly these 2 stores, then publish flag. Nothing else
      // is issued after this -> next poll's vmcnt(0) covers only the poll load.
      asm volatile("s_waitcnt vmcnt(0)" ::: "memory");
      if (lane == 0){
        int val = t + 1;
        asm volatile("global_store_dword %0, %1, off sc0 sc1"
                     :: "v"(myflag), "v"(val) : "memory");
      }
    } else {
      // prior + KL (flag already published)
      #pragma unroll
      for (int r=0;r<16;++r){
        float P = acc0[r] + acc1[r];
        if (t == 0) P = 0.f;                       // in_p0 is zeros
        float other = __shfl_xor(P, 16, 64);       // pair mu <-> ln lanes
        if (muLane){
          float mu_p  = fast_tanh(P);
          float sig_p = __expf(other);
          float mu_q  = fast_tanh(aqm[r]);
          float sig_q = __expf(aql[r]);
          float dm = mu_q - mu_p;
          kacc += __logf(sig_p + 1e-6f) - __logf(sig_q + 1e-6f) - 0.5f
                + 0.5f*(dm*dm + sig_q*sig_q)/(sig_p*sig_p + 1e-6f);
        }
      }
      if (t+1 < TT){
        #pragma unroll
        for (int r=0;r<16;++r){
          int b = (r&3) + 8*(r>>2) + bof;
          const float* ap = A + ((size_t)b*TT + (t+1))*128u;
          aqm[r] = ap[zidx]; aql[r] = ap[64 + zidx];
        }
      }
    }
  }
  if (isKL){
    #pragma unroll
    for (int s=32; s>0; s>>=1) kacc += __shfl_xor(kacc, s, 64);
    if (lane == 0) atomicAdd(dout + (size_t)BTD, kacc * (1e-3f/64.f));
  }
}

extern "C" void kernel_launch(void* const* d_in, const int* in_sizes, int n_in,
                              void* d_out, int out_size, void* d_ws, size_t ws_size,
                              hipStream_t stream){
  const float* hd        = (const float*)d_in[0];
  const float* A         = (const float*)d_in[1];
  const float* noise     = (const float*)d_in[2];
  const float* Wd        = (const float*)d_in[3];
  const float* Wz        = (const float*)d_in[4];
  const float* Wdz       = (const float*)d_in[5];
  const float* Whd       = (const float*)d_in[6];
  const float* bias      = (const float*)d_in[7];
  const float* init_h    = (const float*)d_in[8];
  const float* init_h_mu = (const float*)d_in[9];
  float* dout = (float*)d_out;

  char* ws = (char*)d_ws;
  unsigned short* z_bf  = (unsigned short*)(ws);                      //  4,194,304 B
  unsigned short* Wu    = (unsigned short*)(ws + 4194304u);           //    589,824 B
  unsigned short* Wp    = (unsigned short*)(ws + 4784128u);           //    655,360 B
  unsigned short* dcomm = (unsigned short*)(ws + 5439488u);           //    262,144 B (8 ring slots)
  int*            flags = (int*)          (ws + 5701632u);            //        128 B
  unsigned short* Ufrag = (unsigned short*)(ws + 5701760u);           // 33,554,432 B

  prep_misc_k<<<1024, 256, 0, stream>>>(A, noise, Wd, Wz, Wdz, Whd, init_h,
                                        z_bf, Wu, Wp, dcomm, flags);
  wnll_k     <<<1,    256, 0, stream>>>(init_h, init_h_mu, dout);
  gemm_u_k   <<<1024, 256, 0, stream>>>(hd, z_bf, Wu, bias, Ufrag);
  recur_k    <<<22,   256, 0, stream>>>(dout, A, init_h, Wp, Ufrag, dcomm, flags);
}

// Round 7
// 3054.213 us; speedup vs baseline: 1.8671x; 1.8671x over previous
//
#include <hip/hip_runtime.h>

typedef float f32x4  __attribute__((ext_vector_type(4)));
typedef float f32x16 __attribute__((ext_vector_type(16)));
typedef short short8 __attribute__((ext_vector_type(8)));
typedef int   intx4  __attribute__((ext_vector_type(4)));

#define TT 1024
#define DD 512
#define BTD (32u*1024u*512u)
#define SLOT_SH 16384      // shorts per slot (32KB); 1024 slots, written once each
#define SENT32 0xAAAAAAAAu // placeholder (real sentinel below)
#define SENTD  0xFF80FF80u

__device__ __forceinline__ unsigned short f2bf(float f){
  unsigned int u = __float_as_uint(f);
  u += 0x7FFFu + ((u >> 16) & 1u);          // round-to-nearest-even
  return (unsigned short)(u >> 16);
}
__device__ __forceinline__ float bf2f(unsigned short s){
  return __uint_as_float(((unsigned)s) << 16);
}
__device__ __forceinline__ float fast_tanh(float x){
  float ax = fabsf(x);
  float e  = __expf(2.0f*ax);
  float r  = 1.0f - 2.0f/(e + 1.0f);
  return x < 0.f ? -r : r;
}
__device__ __forceinline__ unsigned umaxu(unsigned a, unsigned b){ return a > b ? a : b; }

// ---------------- prep: sentinel-fill the 32MB ring (uint4 stores) ----------------
__global__ void prep_ring_k(uint4* __restrict__ p){
  const size_t n = (size_t)TT * SLOT_SH / 8;   // 2,097,152 uint4
  uint4 s = make_uint4(SENTD, SENTD, SENTD, SENTD);
  for (size_t i = blockIdx.x*(size_t)blockDim.x + threadIdx.x; i < n;
       i += (size_t)gridDim.x*blockDim.x)
    p[i] = s;
}

// ---------------- prep: z, packed weights, d_init (fragment layout) ----------------
__global__ void prep_misc_k(const float* __restrict__ A, const float* __restrict__ noise,
                            const float* __restrict__ Wd, const float* __restrict__ Wz,
                            const float* __restrict__ Wdz, const float* __restrict__ Whd,
                            const float* __restrict__ init_h,
                            unsigned short* __restrict__ zbf, unsigned short* __restrict__ Wu,
                            unsigned short* __restrict__ Wp, unsigned short* __restrict__ Wdzp,
                            unsigned short* __restrict__ dinit){
  const unsigned NZ = 2097152u, NWU = 294912u, NWP = 262144u, NWZ = 65536u, ND = 16384u;
  const unsigned NT = NZ + NWU + NWP + NWZ + ND;
  for (unsigned i = blockIdx.x*blockDim.x + threadIdx.x; i < NT; i += gridDim.x*blockDim.x){
    if (i < NZ){                                   // z = tanh(mu_in_q) + noise*exp(ln_q)
      unsigned m = i >> 6, zi = i & 63u;
      float muin = A[(size_t)m*128u + zi];
      float ln   = A[(size_t)m*128u + 64u + zi];
      zbf[i] = f2bf(fast_tanh(muin) + noise[i]*__expf(ln));
    } else if (i < NZ+NWU){                        // Wu[c][kk]: [Whd | Wz], [512][576]
      unsigned j = i - NZ;
      unsigned c = j / 576u, kk = j - c*576u;
      float v = (kk < 512u) ? Whd[(size_t)c*512u + kk] : Wz[(size_t)c*64u + (kk-512u)];
      Wu[j] = f2bf(v);
    } else if (i < NZ+NWU+NWP){                    // Wp[c][k] = Wd, [512][512]
      unsigned j = i - (NZ+NWU);
      Wp[j] = f2bf(Wd[j]);
    } else if (i < NZ+NWU+NWP+NWZ){                // Wdzp = bf16(Wdz), [128][512]
      unsigned j = i - (NZ+NWU+NWP);
      Wdzp[j] = f2bf(Wdz[j]);
    } else {                                       // d_{-1} = tanh(init_h), fragment layout
      unsigned j = i - (NZ+NWU+NWP+NWZ);
      unsigned b = j >> 9, c = j & 511u;
      unsigned idx = ((c>>4)<<9) + (((c>>3)&1u)<<8) + (b<<3) + (c&7u);
      dinit[idx] = f2bf(fast_tanh(init_h[j]));
    }
  }
}

// ---------------- wnll_init_h -> d_out[BTD] ----------------
__global__ void wnll_k(const float* __restrict__ init_h, const float* __restrict__ mu,
                       float* __restrict__ dout){
  __shared__ float red[256];
  float s = 0.f;
  for (unsigned i = threadIdx.x; i < 16384u; i += 256u){
    float x = init_h[i] - mu[i & 511u];
    s += 0.5f*x*x;
  }
  red[threadIdx.x] = s; __syncthreads();
  for (int st = 128; st > 0; st >>= 1){
    if ((int)threadIdx.x < st) red[threadIdx.x] += red[threadIdx.x + st];
    __syncthreads();
  }
  if (threadIdx.x == 0){
    float nll = (red[0] + 16384.0f*0.91893853320467274f) / 512.0f;
    dout[(size_t)BTD] = 1e-3f * nll;
  }
}

// ---------------- U = (X @ Wu^T + bias)/tau  into d_out (f32) ----------------
__global__ __launch_bounds__(256) void gemm_u_k(
    const float* __restrict__ hd,             // [32768][512] f32
    const unsigned short* __restrict__ Xz,    // [32768][64]  bf16
    const unsigned short* __restrict__ Wu,    // [512][576]   bf16
    const float* __restrict__ bias,
    float* __restrict__ dout)
{
  __shared__ __align__(16) unsigned short Xs[128][40];
  __shared__ __align__(16) unsigned short Ws[128][40];
  const int bm = blockIdx.x >> 2;
  const int bn = blockIdx.x & 3;
  const int tid = threadIdx.x;
  const int lane = tid & 63;
  const int wv = tid >> 6;
  const int m0 = (wv >> 1) * 64, c0 = (wv & 1) * 64;
  f32x4 acc[4][4];
  #pragma unroll
  for (int i=0;i<4;++i)
    #pragma unroll
    for (int j=0;j<4;++j)
      #pragma unroll
      for (int r=0;r<4;++r) acc[i][j][r] = 0.f;

  const int sm = tid >> 1;
  const int sk = (tid & 1) * 16;
  for (int kt = 0; kt < 18; ++kt){
    __syncthreads();
    {
      int mg = bm*128 + sm;
      if (kt < 16){
        const float* src = hd + (size_t)mg*512u + (unsigned)(kt*32 + sk);
        uint2 o[4];
        #pragma unroll
        for (int q=0;q<4;++q){
          f32x4 v = *reinterpret_cast<const f32x4*>(src + 4*q);
          o[q].x = (unsigned)f2bf(v[0]) | ((unsigned)f2bf(v[1])<<16);
          o[q].y = (unsigned)f2bf(v[2]) | ((unsigned)f2bf(v[3])<<16);
        }
        *reinterpret_cast<uint4*>(&Xs[sm][sk])   = make_uint4(o[0].x,o[0].y,o[1].x,o[1].y);
        *reinterpret_cast<uint4*>(&Xs[sm][sk+8]) = make_uint4(o[2].x,o[2].y,o[3].x,o[3].y);
      } else {
        const unsigned short* src = Xz + (size_t)mg*64u + (unsigned)((kt-16)*32 + sk);
        uint4 v0 = *reinterpret_cast<const uint4*>(src);
        uint4 v1 = *reinterpret_cast<const uint4*>(src + 8);
        *reinterpret_cast<uint4*>(&Xs[sm][sk])   = v0;
        *reinterpret_cast<uint4*>(&Xs[sm][sk+8]) = v1;
      }
      int cg = bn*128 + sm;
      const unsigned short* wsrc = Wu + (size_t)cg*576u + (unsigned)(kt*32 + sk);
      uint4 w0 = *reinterpret_cast<const uint4*>(wsrc);
      uint4 w1 = *reinterpret_cast<const uint4*>(wsrc + 8);
      *reinterpret_cast<uint4*>(&Ws[sm][sk])   = w0;
      *reinterpret_cast<uint4*>(&Ws[sm][sk+8]) = w1;
    }
    __syncthreads();
    short8 af[4], bf[4];
    #pragma unroll
    for (int i=0;i<4;++i)
      af[i] = *reinterpret_cast<const short8*>(&Xs[m0 + i*16 + (lane&15)][(lane>>4)*8]);
    #pragma unroll
    for (int j=0;j<4;++j)
      bf[j] = *reinterpret_cast<const short8*>(&Ws[c0 + j*16 + (lane&15)][(lane>>4)*8]);
    #pragma unroll
    for (int i=0;i<4;++i)
      #pragma unroll
      for (int j=0;j<4;++j)
        acc[i][j] = __builtin_amdgcn_mfma_f32_16x16x32_bf16(af[i], bf[j], acc[i][j], 0, 0, 0);
  }
  #pragma unroll
  for (int j=0;j<4;++j){
    int cg = bn*128 + c0 + j*16 + (lane&15);
    float bia  = bias[cg];
    float itau = (cg < 256) ? 0.25f : 0.5f;
    #pragma unroll
    for (int i=0;i<4;++i){
      int mbase = bm*128 + m0 + i*16 + (lane>>4)*4;
      #pragma unroll
      for (int r=0;r<4;++r)
        dout[(size_t)(mbase + r)*512u + cg] = (acc[i][j][r] + bia) * itau;
    }
  }
}

// ---------------- persistent serial recurrence: sentinel-sync, write-once ring ----------------
// grid = 20 WGs x 256.  WG 0..15 (wave 0): D-column workers, 32 cols each.
// WG 16..19 (4 waves): d_seq writers, 16 wave-portions of 2KB per slot.
// Ring: 1024 slots (one per step), each written EXACTLY once -> monotone,
// no reuse, no re-sentinel, deadlock-free. Valid data dwords < 0xC0000000u
// (bf16 tanh outputs); sentinel 0xFF80FF80. All ring traffic sc0 sc1.
__global__ __launch_bounds__(256,1) void recur_k(
    float* __restrict__ dout, const float* __restrict__ init_h,
    const unsigned short* __restrict__ Wp, const unsigned short* __restrict__ dinit,
    unsigned short* __restrict__ dcomm)
{
  __shared__ __align__(16) unsigned short tl[32][40];
  const int wg = blockIdx.x;

  // ================= writer WGs (16 waves across 4 WGs) =================
  if (wg >= 16){
    const int tid  = threadIdx.x;
    const int lane = tid & 63;
    const int wid  = (wg - 16)*4 + (tid >> 6);    // 0..15, owns 2KB of each slot
    const int b    = lane & 31;
    const int cb0  = wid*32 + (lane>>5)*8;        // load1 cols; load2 at +16
    for (int t = 0; t < TT; ++t){
      const char* base = (const char*)dcomm + (size_t)t*32768 + wid*2048 + lane*16;
      intx4 q0, q1;
      for (;;){
        asm volatile(
          "global_load_dwordx4 %0, %2, off sc0 sc1\n\t"
          "global_load_dwordx4 %1, %2, off offset:1024 sc0 sc1\n\t"
          "s_waitcnt vmcnt(0)"
          : "=&v"(q0), "=&v"(q1) : "v"(base) : "memory");
        unsigned mx = umaxu(umaxu(umaxu((unsigned)q0[0],(unsigned)q0[1]),
                                  umaxu((unsigned)q0[2],(unsigned)q0[3])),
                            umaxu(umaxu((unsigned)q1[0],(unsigned)q1[1]),
                                  umaxu((unsigned)q1[2],(unsigned)q1[3])));
        if (__all(mx < 0xC0000000u)) break;
      }
      __builtin_amdgcn_sched_barrier(0);
      float* drow = dout + ((size_t)b*TT + t)*DD;
      union { intx4 i; short8 s; } c0, c1; c0.i = q0; c1.i = q1;
      f32x4 o0, o1, o2, o3;
      #pragma unroll
      for (int e=0;e<4;++e){
        o0[e] = bf2f((unsigned short)c0.s[e]);
        o1[e] = bf2f((unsigned short)c0.s[4+e]);
        o2[e] = bf2f((unsigned short)c1.s[e]);
        o3[e] = bf2f((unsigned short)c1.s[4+e]);
      }
      *reinterpret_cast<f32x4*>(drow + cb0)          = o0;
      *reinterpret_cast<f32x4*>(drow + cb0 + 4)      = o1;
      *reinterpret_cast<f32x4*>(drow + cb0 + 16)     = o2;
      *reinterpret_cast<f32x4*>(drow + cb0 + 16 + 4) = o3;
    }
    return;
  }

  // ================= worker WGs (wave 0 only) =================
  if (threadIdx.x >= 64) return;
  const int lane = threadIdx.x;
  const int pc    = wg*32 + (lane & 31);      // D column 0..511
  const int khalf = (lane >> 5) * 8;
  const int bof   = (lane >> 5) * 4;

  short8 wfrag[32];
  #pragma unroll
  for (int kc = 0; kc < 32; ++kc)
    wfrag[kc] = *reinterpret_cast<const short8*>(Wp + (size_t)pc*512u + (unsigned)(kc*16 + khalf));

  const float dec  = (pc < 256) ? 0.75f : 0.5f;
  const float itau = (pc < 256) ? 0.25f : 0.5f;

  float h[16];
  #pragma unroll
  for (int r=0;r<16;++r){
    int b = (r&3) + 8*(r>>2) + bof;
    h[r] = init_h[b*512 + pc];
  }

  // prefetch U for step 0 (plain cached; gemm_u wrote dout)
  float u[16];
  #pragma unroll
  for (int r=0;r<16;++r){
    int b = (r&3) + 8*(r>>2) + bof;
    u[r] = dout[((size_t)b*TT + 0)*DD + pc];
  }

  union CV { intx4 i; short8 s; };

  for (int t = 0; t < TT; ++t){
    // gather d_{t-1}: spin until sentinel-free (write-once slot => monotone)
    const char* gbase = (t == 0)
        ? (const char*)dinit
        : (const char*)dcomm + (size_t)(t-1)*32768;
    const char* base = gbase + lane*16;
    intx4 fi[32];
    for (;;){
      #pragma unroll
      for (int g = 0; g < 8; ++g){
        const char* bp = base + g*4096;
        asm volatile(
          "global_load_dwordx4 %0, %4, off sc0 sc1\n\t"
          "global_load_dwordx4 %1, %4, off offset:1024 sc0 sc1\n\t"
          "global_load_dwordx4 %2, %4, off offset:2048 sc0 sc1\n\t"
          "global_load_dwordx4 %3, %4, off offset:3072 sc0 sc1"
          : "=&v"(fi[4*g]), "=&v"(fi[4*g+1]), "=&v"(fi[4*g+2]), "=&v"(fi[4*g+3])
          : "v"(bp) : "memory");
      }
      asm volatile("s_waitcnt vmcnt(0)" ::: "memory");
      unsigned mx = 0u;
      #pragma unroll
      for (int j=0;j<32;++j){
        mx = umaxu(mx, umaxu(umaxu((unsigned)fi[j][0],(unsigned)fi[j][1]),
                             umaxu((unsigned)fi[j][2],(unsigned)fi[j][3])));
      }
      if (__all(mx < 0xC0000000u)) break;
    }
    __builtin_amdgcn_sched_barrier(0);

    // prefetch next step's U (hides under MFMA)
    float un[16];
    if (t+1 < TT){
      #pragma unroll
      for (int r=0;r<16;++r){
        int b = (r&3) + 8*(r>>2) + bof;
        un[r] = dout[((size_t)b*TT + (t+1))*DD + pc];
      }
    }

    // P = d_{t-1} @ W_slice  (two interleaved MFMA chains)
    f32x16 acc0, acc1;
    #pragma unroll
    for (int q=0;q<16;++q){ acc0[q]=0.f; acc1[q]=0.f; }
    #pragma unroll
    for (int kc=0;kc<16;++kc){
      CV c0, c1; c0.i = fi[2*kc]; c1.i = fi[2*kc+1];
      acc0 = __builtin_amdgcn_mfma_f32_32x32x16_bf16(c0.s, wfrag[2*kc  ], acc0, 0, 0, 0);
      acc1 = __builtin_amdgcn_mfma_f32_32x32x16_bf16(c1.s, wfrag[2*kc+1], acc1, 0, 0, 0);
    }

    float dv[16];
    #pragma unroll
    for (int r=0;r<16;++r){
      float P = acc0[r] + acc1[r];
      h[r]  = dec*h[r] + P*itau + u[r];
      dv[r] = fast_tanh(h[r]);
    }
    // in-wave transpose via LDS: tl[batch][local col]
    #pragma unroll
    for (int r=0;r<16;++r){
      int b = (r&3) + 8*(r>>2) + bof;
      tl[b][lane & 31] = f2bf(dv[r]);
    }
    // two coalesced b128 uncached stores into fragment-layout slot; fire-and-forget
    {
      unsigned short* ds = dcomm + (size_t)t*SLOT_SH + (2*wg)*512 + lane*8;
      short8 s0 = *reinterpret_cast<const short8*>(&tl[lane & 31][khalf]);
      short8 s1 = *reinterpret_cast<const short8*>(&tl[lane & 31][16 + khalf]);
      asm volatile("global_store_dwordx4 %0, %2, off sc0 sc1\n\t"
                   "global_store_dwordx4 %1, %3, off sc0 sc1"
                   :: "v"(ds), "v"(ds + 512), "v"(s0), "v"(s1) : "memory");
    }
    if (t+1 < TT){
      #pragma unroll
      for (int r=0;r<16;++r) u[r] = un[r];
    }
  }
}

// ---------------- epilogue: prior_in = d_shifted @ Wdz^T, fused KL -> atomicAdd ----------------
__global__ __launch_bounds__(256) void gemm_p_k(
    const float* __restrict__ dseq,           // dout: [32][1024][512] f32
    const unsigned short* __restrict__ Wdzp,  // [128][512] bf16
    const float* __restrict__ A,              // [32768][128] f32
    float* __restrict__ dout)
{
  __shared__ __align__(16) unsigned short Xs[128][40];
  __shared__ __align__(16) unsigned short Ws[128][40];
  __shared__ float Ls[128][128];
  __shared__ float red[256];
  const int bm = blockIdx.x;
  const int tid = threadIdx.x;
  const int lane = tid & 63;
  const int wv = tid >> 6;
  const int m0 = (wv >> 1) * 64, c0 = (wv & 1) * 64;
  f32x4 acc[4][4];
  #pragma unroll
  for (int i=0;i<4;++i)
    #pragma unroll
    for (int j=0;j<4;++j)
      #pragma unroll
      for (int r=0;r<4;++r) acc[i][j][r] = 0.f;

  const int sm = tid >> 1;
  const int sk = (tid & 1) * 16;
  for (int kt = 0; kt < 16; ++kt){
    __syncthreads();
    {
      int mg = bm*128 + sm;
      int ttm = mg & 1023;
      int srow = (ttm == 0) ? mg : (mg - 1);       // d[b][t-1]; t==0 rows overridden in KL
      const float* src = dseq + (size_t)srow*512u + (unsigned)(kt*32 + sk);
      uint2 o[4];
      #pragma unroll
      for (int q=0;q<4;++q){
        f32x4 v = *reinterpret_cast<const f32x4*>(src + 4*q);
        o[q].x = (unsigned)f2bf(v[0]) | ((unsigned)f2bf(v[1])<<16);
        o[q].y = (unsigned)f2bf(v[2]) | ((unsigned)f2bf(v[3])<<16);
      }
      *reinterpret_cast<uint4*>(&Xs[sm][sk])   = make_uint4(o[0].x,o[0].y,o[1].x,o[1].y);
      *reinterpret_cast<uint4*>(&Xs[sm][sk+8]) = make_uint4(o[2].x,o[2].y,o[3].x,o[3].y);
      const unsigned short* wsrc = Wdzp + (size_t)sm*512u + (unsigned)(kt*32 + sk);
      uint4 w0 = *reinterpret_cast<const uint4*>(wsrc);
      uint4 w1 = *reinterpret_cast<const uint4*>(wsrc + 8);
      *reinterpret_cast<uint4*>(&Ws[sm][sk])   = w0;
      *reinterpret_cast<uint4*>(&Ws[sm][sk+8]) = w1;
    }
    __syncthreads();
    short8 af[4], bf[4];
    #pragma unroll
    for (int i=0;i<4;++i)
      af[i] = *reinterpret_cast<const short8*>(&Xs[m0 + i*16 + (lane&15)][(lane>>4)*8]);
    #pragma unroll
    for (int j=0;j<4;++j)
      bf[j] = *reinterpret_cast<const short8*>(&Ws[c0 + j*16 + (lane&15)][(lane>>4)*8]);
    #pragma unroll
    for (int i=0;i<4;++i)
      #pragma unroll
      for (int j=0;j<4;++j)
        acc[i][j] = __builtin_amdgcn_mfma_f32_16x16x32_bf16(af[i], bf[j], acc[i][j], 0, 0, 0);
  }
  // acc -> LDS tile [128m][128c]
  #pragma unroll
  for (int j=0;j<4;++j){
    int cc = c0 + j*16 + (lane&15);
    #pragma unroll
    for (int i=0;i<4;++i){
      int mm = m0 + i*16 + (lane>>4)*4;
      #pragma unroll
      for (int r=0;r<4;++r)
        Ls[mm + r][cc] = acc[i][j][r];
    }
  }
  __syncthreads();
  // fused KL: element (m, z) uses Ls[m][z] (mu_in) and Ls[m][64+z] (lnsigma)
  float ks = 0.f;
  const int z = tid & 63;
  for (int ml = (tid >> 6); ml < 128; ml += 4){
    int mg = bm*128 + ml;
    int ttm = mg & 1023;
    const float* ap = A + (size_t)mg*128u;
    float mq = fast_tanh(ap[z]);
    float sq = __expf(ap[64 + z]);
    float mp = (ttm == 0) ? 0.f : fast_tanh(Ls[ml][z]);
    float sp = (ttm == 0) ? 1.f : __expf(Ls[ml][64 + z]);
    float dm = mq - mp;
    ks += __logf(sp + 1e-6f) - __logf(sq + 1e-6f) - 0.5f
        + 0.5f*(dm*dm + sq*sq)/(sp*sp + 1e-6f);
  }
  red[tid] = ks; __syncthreads();
  for (int st = 128; st > 0; st >>= 1){
    if (tid < st) red[tid] += red[tid + st];
    __syncthreads();
  }
  if (tid == 0) atomicAdd(dout + (size_t)BTD, red[0] * (1e-3f/64.f));
}

extern "C" void kernel_launch(void* const* d_in, const int* in_sizes, int n_in,
                              void* d_out, int out_size, void* d_ws, size_t ws_size,
                              hipStream_t stream){
  const float* hd        = (const float*)d_in[0];
  const float* A         = (const float*)d_in[1];
  const float* noise     = (const float*)d_in[2];
  const float* Wd        = (const float*)d_in[3];
  const float* Wz        = (const float*)d_in[4];
  const float* Wdz       = (const float*)d_in[5];
  const float* Whd       = (const float*)d_in[6];
  const float* bias      = (const float*)d_in[7];
  const float* init_h    = (const float*)d_in[8];
  const float* init_h_mu = (const float*)d_in[9];
  float* dout = (float*)d_out;

  char* ws = (char*)d_ws;
  unsigned short* z_bf  = (unsigned short*)(ws);                      //  4,194,304 B
  unsigned short* Wu    = (unsigned short*)(ws + 4194304u);           //    589,824 B
  unsigned short* Wp    = (unsigned short*)(ws + 4784128u);           //    524,288 B
  unsigned short* Wdzp  = (unsigned short*)(ws + 5308416u);           //    131,072 B
  unsigned short* dinit = (unsigned short*)(ws + 5439488u);           //     32,768 B
  unsigned short* dcomm = (unsigned short*)(ws + 5472256u);           // 33,554,432 B (1024 slots)
  // total 39,026,688 B

  prep_ring_k<<<2048, 256, 0, stream>>>((uint4*)dcomm);
  prep_misc_k<<<1024, 256, 0, stream>>>(A, noise, Wd, Wz, Wdz, Whd, init_h,
                                        z_bf, Wu, Wp, Wdzp, dinit);
  wnll_k     <<<1,    256, 0, stream>>>(init_h, init_h_mu, dout);
  gemm_u_k   <<<1024, 256, 0, stream>>>(hd, z_bf, Wu, bias, dout);
  recur_k    <<<20,   256, 0, stream>>>(dout, init_h, Wp, dinit, dcomm);
  gemm_p_k   <<<256,  256, 0, stream>>>(dout, Wdzp, A, dout);
}